// Round 1
// baseline (800.955 us; speedup 1.0000x reference)
//
#include <hip/hip_runtime.h>
#include <hip/hip_bf16.h>
#include <stdint.h>

typedef __attribute__((ext_vector_type(8))) short bf16x8;
typedef __attribute__((ext_vector_type(4))) float f32x4;
typedef __attribute__((ext_vector_type(2))) float f32x2;

__device__ __forceinline__ uint16_t f2bf(float f) {
    __bf16 h = (__bf16)f;                 // HW RNE convert (scalar cast compiles well on gfx950)
    return __builtin_bit_cast(uint16_t, h);
}
__device__ __forceinline__ float bf2f(uint16_t h) {
    uint32_t u = ((uint32_t)h) << 16;
    return __builtin_bit_cast(float, u);
}
__device__ __forceinline__ bf16x8 pack8(f32x4 a, f32x4 b) {
    union { bf16x8 v; uint16_t s[8]; } o;
    o.s[0] = f2bf(a[0]); o.s[1] = f2bf(a[1]); o.s[2] = f2bf(a[2]); o.s[3] = f2bf(a[3]);
    o.s[4] = f2bf(b[0]); o.s[5] = f2bf(b[1]); o.s[6] = f2bf(b[2]); o.s[7] = f2bf(b[3]);
    return o.v;
}

// ---------------------------------------------------------------------------
// K1: qkv = x @ qkv_w^T + qkv_b   (M=4096, N=2304, K=768), fp32 in, bf16 out
// writes q[b,h,n,d], k[b,h,n,d], vT[b,h,d,n]
// grid (32, 18), block 256
// ---------------------------------------------------------------------------
__global__ __launch_bounds__(256) void k_qkv(
    const float* __restrict__ x, const float* __restrict__ w,
    const float* __restrict__ bias, uint16_t* __restrict__ qb,
    uint16_t* __restrict__ kb, uint16_t* __restrict__ vtb)
{
    __shared__ uint16_t As[128][40];   // pad 32 -> 40 (2-way max bank conflict)
    __shared__ uint16_t Bs[128][40];
    const int t = threadIdx.x;
    const int lane = t & 63;
    const int wv = t >> 6, wr = wv >> 1, wc = wv & 1;
    const int row0 = blockIdx.x * 128, col0 = blockIdx.y * 128;
    const int sr = t >> 1, sc = (t & 1) << 4;     // staging: row sr, cols sc..sc+15
    const float* xa = x + (size_t)(row0 + sr) * 768 + sc;
    const float* wa = w + (size_t)(col0 + sr) * 768 + sc;

    f32x4 ra[4], rb[4];
#pragma unroll
    for (int i = 0; i < 4; ++i) { ra[i] = *(const f32x4*)(xa + i * 4); rb[i] = *(const f32x4*)(wa + i * 4); }

    f32x4 acc[4][4];
    const f32x4 z = {0.f, 0.f, 0.f, 0.f};
#pragma unroll
    for (int i = 0; i < 4; ++i)
#pragma unroll
        for (int j = 0; j < 4; ++j) acc[i][j] = z;

    const int fr = lane & 15, fo = (lane >> 4) << 3;

    for (int kt = 0; kt < 24; ++kt) {
        __syncthreads();
        *(bf16x8*)&As[sr][sc]     = pack8(ra[0], ra[1]);
        *(bf16x8*)&As[sr][sc + 8] = pack8(ra[2], ra[3]);
        *(bf16x8*)&Bs[sr][sc]     = pack8(rb[0], rb[1]);
        *(bf16x8*)&Bs[sr][sc + 8] = pack8(rb[2], rb[3]);
        __syncthreads();
        if (kt < 23) {
            xa += 32; wa += 32;
#pragma unroll
            for (int i = 0; i < 4; ++i) { ra[i] = *(const f32x4*)(xa + i * 4); rb[i] = *(const f32x4*)(wa + i * 4); }
        }
        bf16x8 af[4], bfv[4];
#pragma unroll
        for (int mi = 0; mi < 4; ++mi) af[mi]  = *(const bf16x8*)&As[wr * 64 + mi * 16 + fr][fo];
#pragma unroll
        for (int ni = 0; ni < 4; ++ni) bfv[ni] = *(const bf16x8*)&Bs[wc * 64 + ni * 16 + fr][fo];
#pragma unroll
        for (int mi = 0; mi < 4; ++mi)
#pragma unroll
            for (int ni = 0; ni < 4; ++ni)
                acc[mi][ni] = __builtin_amdgcn_mfma_f32_16x16x32_bf16(af[mi], bfv[ni], acc[mi][ni], 0, 0, 0);
    }

    const int rgr = (lane >> 4) << 2;
#pragma unroll
    for (int ni = 0; ni < 4; ++ni) {
        const int Jc = col0 + wc * 64 + ni * 16 + fr;
        const float bv = bias[Jc];
        const int which = Jc / 768;
        const int rem = Jc - which * 768;
        const int h = rem >> 6, d = rem & 63;
#pragma unroll
        for (int mi = 0; mi < 4; ++mi) {
#pragma unroll
            for (int i = 0; i < 4; ++i) {
                const int R = row0 + wr * 64 + mi * 16 + rgr + i;
                const int b = R >> 10, n = R & 1023;
                const uint16_t hv = f2bf(acc[mi][ni][i] + bv);
                if (which == 0)      qb [((size_t)(b * 12 + h) * 1024 + n) * 64 + d] = hv;
                else if (which == 1) kb [((size_t)(b * 12 + h) * 1024 + n) * 64 + d] = hv;
                else                 vtb[((size_t)(b * 12 + h) * 64 + d) * 1024 + n] = hv;
            }
        }
    }
}

// ---------------------------------------------------------------------------
// K2: S[bh, n, m] = sum_d q[bh,n,d] * k[bh,m,d]   (raw scores, bf16 out)
// grid (8, 8, 48), block 256
// ---------------------------------------------------------------------------
__global__ __launch_bounds__(256) void k_qk(
    const uint16_t* __restrict__ q, const uint16_t* __restrict__ k,
    uint16_t* __restrict__ S)
{
    const int t = threadIdx.x, lane = t & 63;
    const int wv = t >> 6, wr = wv >> 1, wc = wv & 1;
    const int bh = blockIdx.z;
    q += (size_t)bh << 16;        // 1024*64
    k += (size_t)bh << 16;
    S += (size_t)bh << 20;        // 1024*1024
    const int R0 = blockIdx.x * 128 + wr * 64;
    const int C0 = blockIdx.y * 128 + wc * 64;
    const int fr = lane & 15, fo = (lane >> 4) << 3;

    bf16x8 af[4][2], bfv[4][2];
#pragma unroll
    for (int mi = 0; mi < 4; ++mi)
#pragma unroll
        for (int ks = 0; ks < 2; ++ks)
            af[mi][ks] = *(const bf16x8*)(q + (R0 + mi * 16 + fr) * 64 + ks * 32 + fo);
#pragma unroll
    for (int ni = 0; ni < 4; ++ni)
#pragma unroll
        for (int ks = 0; ks < 2; ++ks)
            bfv[ni][ks] = *(const bf16x8*)(k + (C0 + ni * 16 + fr) * 64 + ks * 32 + fo);

    f32x4 acc[4][4];
    const f32x4 z = {0.f, 0.f, 0.f, 0.f};
#pragma unroll
    for (int i = 0; i < 4; ++i)
#pragma unroll
        for (int j = 0; j < 4; ++j) acc[i][j] = z;
#pragma unroll
    for (int mi = 0; mi < 4; ++mi)
#pragma unroll
        for (int ni = 0; ni < 4; ++ni) {
            acc[mi][ni] = __builtin_amdgcn_mfma_f32_16x16x32_bf16(af[mi][0], bfv[ni][0], acc[mi][ni], 0, 0, 0);
            acc[mi][ni] = __builtin_amdgcn_mfma_f32_16x16x32_bf16(af[mi][1], bfv[ni][1], acc[mi][ni], 0, 0, 0);
        }

    const int rgr = (lane >> 4) << 2;
#pragma unroll
    for (int mi = 0; mi < 4; ++mi)
#pragma unroll
        for (int ni = 0; ni < 4; ++ni)
#pragma unroll
            for (int i = 0; i < 4; ++i) {
                const int R = R0 + mi * 16 + rgr + i;
                const int C = C0 + ni * 16 + fr;
                S[(size_t)R * 1024 + C] = f2bf(acc[mi][ni][i]);
            }
}

// ---------------------------------------------------------------------------
// K3: per (b,n) row: softmax over m per head, uncertainty = sigmoid(du_w @ qk + du_b),
//     attn = softmax + unc * r (bf16, in-place over S). Writes attn_mean/unc fp32.
// grid 4096, block 512 (each thread owns m = {2t, 2t+1} for all 12 heads)
// ---------------------------------------------------------------------------
__global__ __launch_bounds__(512) void k_soft(
    uint16_t* __restrict__ S, const float* __restrict__ r,
    const float* __restrict__ du_w, const float* __restrict__ du_b,
    float* __restrict__ am, float* __restrict__ un)
{
    const int bn = blockIdx.x;
    const int b = bn >> 10, n = bn & 1023;
    const int t = threadIdx.x;
    const int lane = t & 63, wv = t >> 6;

    __shared__ float sdw[144];
    __shared__ float sdb[12];
    __shared__ float red[8][12];
    __shared__ float bmax[12];
    __shared__ float binv[12];
    if (t < 144) sdw[t] = du_w[t];
    if (t < 12)  sdb[t] = du_b[t];

    const size_t pbase = ((size_t)(b * 12) * 1024 + n) * 1024;  // + (h<<20) + m
    const int m0 = t * 2;

    float s[12][2];
#pragma unroll
    for (int h = 0; h < 12; ++h) {
        const uint32_t u = *(const uint32_t*)(S + pbase + ((size_t)h << 20) + m0);
        s[h][0] = bf2f((uint16_t)(u & 0xFFFFu));
        s[h][1] = bf2f((uint16_t)(u >> 16));
    }

    // block max per head
    float lm[12];
#pragma unroll
    for (int h = 0; h < 12; ++h) lm[h] = fmaxf(s[h][0], s[h][1]);
#pragma unroll
    for (int off = 32; off >= 1; off >>= 1)
#pragma unroll
        for (int h = 0; h < 12; ++h) lm[h] = fmaxf(lm[h], __shfl_xor(lm[h], off));
    if (lane == 0)
#pragma unroll
        for (int h = 0; h < 12; ++h) red[wv][h] = lm[h];
    __syncthreads();
    if (t < 12) {
        float m = red[0][t];
#pragma unroll
        for (int w2 = 1; w2 < 8; ++w2) m = fmaxf(m, red[w2][t]);
        bmax[t] = m;
    }
    __syncthreads();

    // exp + block sum per head
    const float CE = 0.125f * 1.44269504088896f;   // scale * log2(e)
    float p[12][2], ls[12];
#pragma unroll
    for (int h = 0; h < 12; ++h) {
        const float mx = bmax[h];
        p[h][0] = exp2f((s[h][0] - mx) * CE);
        p[h][1] = exp2f((s[h][1] - mx) * CE);
        ls[h] = p[h][0] + p[h][1];
    }
#pragma unroll
    for (int off = 32; off >= 1; off >>= 1)
#pragma unroll
        for (int h = 0; h < 12; ++h) ls[h] += __shfl_xor(ls[h], off);
    if (lane == 0)
#pragma unroll
        for (int h = 0; h < 12; ++h) red[wv][h] = ls[h];
    __syncthreads();
    if (t < 12) {
        float sm = 0.f;
#pragma unroll
        for (int w2 = 0; w2 < 8; ++w2) sm += red[w2][t];
        binv[t] = 1.f / sm;
    }
    __syncthreads();

    const float L2E = 1.44269504088896f;
#pragma unroll
    for (int o = 0; o < 12; ++o) {
        float a0 = sdb[o], a1 = sdb[o];
#pragma unroll
        for (int h = 0; h < 12; ++h) {
            const float wv_ = sdw[o * 12 + h];
            a0 += wv_ * s[h][0];
            a1 += wv_ * s[h][1];
        }
        const float u0 = 1.f / (1.f + exp2f(-a0 * L2E));
        const float u1 = 1.f / (1.f + exp2f(-a1 * L2E));
        const float inv = binv[o];
        const float p0 = p[o][0] * inv, p1 = p[o][1] * inv;
        const size_t idx = pbase + ((size_t)o << 20) + m0;
        f32x2 pm; pm[0] = p0; pm[1] = p1;
        *(f32x2*)(am + idx) = pm;
        f32x2 uo; uo[0] = u0; uo[1] = u1;
        *(f32x2*)(un + idx) = uo;
        const f32x2 rv = *(const f32x2*)(r + idx);
        const uint32_t pk = (uint32_t)f2bf(p0 + u0 * rv[0]) | ((uint32_t)f2bf(p1 + u1 * rv[1]) << 16);
        *(uint32_t*)(S + idx) = pk;
    }
}

// ---------------------------------------------------------------------------
// K4: out_h[b,n,h*64+d] = sum_m attn[bh,n,m] * vT[bh,d,m]  (bf16 out)
// grid (8, 48), block 256 (4 waves x 32 rows)
// ---------------------------------------------------------------------------
__global__ __launch_bounds__(256) void k_pv(
    const uint16_t* __restrict__ attn, const uint16_t* __restrict__ vt,
    uint16_t* __restrict__ oh)
{
    const int t = threadIdx.x, lane = t & 63, wv = t >> 6;
    const int bh = blockIdx.y, b = bh / 12, h = bh - b * 12;
    attn += (size_t)bh << 20;
    vt   += (size_t)bh << 16;
    const int R0 = blockIdx.x * 128 + wv * 32;
    const int fr = lane & 15, fo = (lane >> 4) << 3;

    f32x4 acc[2][4];
    const f32x4 z = {0.f, 0.f, 0.f, 0.f};
#pragma unroll
    for (int i = 0; i < 2; ++i)
#pragma unroll
        for (int j = 0; j < 4; ++j) acc[i][j] = z;

    for (int kk = 0; kk < 32; ++kk) {
        const int k0 = kk * 32;
        bf16x8 af[2], bfv[4];
#pragma unroll
        for (int mi = 0; mi < 2; ++mi)
            af[mi] = *(const bf16x8*)(attn + (size_t)(R0 + mi * 16 + fr) * 1024 + k0 + fo);
#pragma unroll
        for (int ni = 0; ni < 4; ++ni)
            bfv[ni] = *(const bf16x8*)(vt + (size_t)(ni * 16 + fr) * 1024 + k0 + fo);
#pragma unroll
        for (int mi = 0; mi < 2; ++mi)
#pragma unroll
            for (int ni = 0; ni < 4; ++ni)
                acc[mi][ni] = __builtin_amdgcn_mfma_f32_16x16x32_bf16(af[mi], bfv[ni], acc[mi][ni], 0, 0, 0);
    }

    const int rgr = (lane >> 4) << 2;
#pragma unroll
    for (int mi = 0; mi < 2; ++mi)
#pragma unroll
        for (int ni = 0; ni < 4; ++ni)
#pragma unroll
            for (int i = 0; i < 4; ++i) {
                const int R = R0 + mi * 16 + rgr + i;
                const int d = ni * 16 + fr;
                oh[((size_t)b * 1024 + R) * 768 + h * 64 + d] = f2bf(acc[mi][ni][i]);
            }
}

// ---------------------------------------------------------------------------
// K5: out = out_h @ proj_w^T + proj_b   (M=4096, N=768, K=768), fp32 out
// grid (32, 12), block 256 (4 waves 2x2, wave = 64 rows x 32 cols)
// ---------------------------------------------------------------------------
__global__ __launch_bounds__(256) void k_proj(
    const uint16_t* __restrict__ a, const float* __restrict__ w,
    const float* __restrict__ bias, float* __restrict__ out)
{
    const int t = threadIdx.x, lane = t & 63;
    const int wv = t >> 6, wr = wv >> 1, wc = wv & 1;
    const int R0 = blockIdx.x * 128 + wr * 64;
    const int J0 = blockIdx.y * 64 + wc * 32;
    const int fr = lane & 15, fo = (lane >> 4) << 3;

    f32x4 acc[4][2];
    const f32x4 z = {0.f, 0.f, 0.f, 0.f};
#pragma unroll
    for (int i = 0; i < 4; ++i) { acc[i][0] = z; acc[i][1] = z; }

    for (int kk = 0; kk < 24; ++kk) {
        const int k0 = kk * 32;
        bf16x8 af[4], bfv[2];
#pragma unroll
        for (int mi = 0; mi < 4; ++mi)
            af[mi] = *(const bf16x8*)(a + (size_t)(R0 + mi * 16 + fr) * 768 + k0 + fo);
#pragma unroll
        for (int ni = 0; ni < 2; ++ni) {
            const float* wp = w + (size_t)(J0 + ni * 16 + fr) * 768 + k0 + fo;
            bfv[ni] = pack8(*(const f32x4*)wp, *(const f32x4*)(wp + 4));
        }
#pragma unroll
        for (int mi = 0; mi < 4; ++mi)
#pragma unroll
            for (int ni = 0; ni < 2; ++ni)
                acc[mi][ni] = __builtin_amdgcn_mfma_f32_16x16x32_bf16(af[mi], bfv[ni], acc[mi][ni], 0, 0, 0);
    }

    const int rgr = (lane >> 4) << 2;
#pragma unroll
    for (int ni = 0; ni < 2; ++ni) {
        const int Jc = J0 + ni * 16 + fr;
        const float bv = bias[Jc];
#pragma unroll
        for (int mi = 0; mi < 4; ++mi)
#pragma unroll
            for (int i = 0; i < 4; ++i) {
                const int R = R0 + mi * 16 + rgr + i;
                out[(size_t)R * 768 + Jc] = acc[mi][ni][i] + bv;
            }
    }
}

// ---------------------------------------------------------------------------
extern "C" void kernel_launch(void* const* d_in, const int* in_sizes, int n_in,
                              void* d_out, int out_size, void* d_ws, size_t ws_size,
                              hipStream_t stream)
{
    const float* x      = (const float*)d_in[0];
    const float* r      = (const float*)d_in[1];
    const float* qkv_w  = (const float*)d_in[2];
    const float* qkv_b  = (const float*)d_in[3];
    const float* proj_w = (const float*)d_in[4];
    const float* proj_b = (const float*)d_in[5];
    const float* du_w   = (const float*)d_in[6];
    const float* du_b   = (const float*)d_in[7];

    float* out       = (float*)d_out;                    // [4,1024,768]
    float* attn_mean = out + 3145728;                    // [4,12,1024,1024]
    float* unc       = attn_mean + 50331648;             // [4,12,1024,1024]

    uint16_t* ws  = (uint16_t*)d_ws;
    uint16_t* qb  = ws;                 // 3145728 elems  q[b,h,n,d]
    uint16_t* kb  = qb + 3145728;       // 3145728        k[b,h,n,d]
    uint16_t* vtb = kb + 3145728;       // 3145728        vT[b,h,d,n]
    uint16_t* S   = vtb + 3145728;      // 50331648       qk scores -> attn (in place)
    uint16_t* oh  = S + 50331648;       // 3145728        out_h[b,n,h*64+d]

    k_qkv <<<dim3(32, 18), 256, 0, stream>>>(x, qkv_w, qkv_b, qb, kb, vtb);
    k_qk  <<<dim3(8, 8, 48), 256, 0, stream>>>(qb, kb, S);
    k_soft<<<dim3(4096), 512, 0, stream>>>(S, r, du_w, du_b, attn_mean, unc);
    k_pv  <<<dim3(8, 48), 256, 0, stream>>>(S, vtb, oh);
    k_proj<<<dim3(32, 12), 256, 0, stream>>>(oh, proj_w, proj_b, out);
}

// Round 3
// 752.297 us; speedup vs baseline: 1.0647x; 1.0647x over previous
//
#include <hip/hip_runtime.h>
#include <hip/hip_bf16.h>
#include <stdint.h>

typedef __attribute__((ext_vector_type(8))) short bf16x8;
typedef __attribute__((ext_vector_type(4))) float f32x4;
typedef __attribute__((ext_vector_type(2))) float f32x2;

__device__ __forceinline__ uint16_t f2bf(float f) {
    __bf16 h = (__bf16)f;
    return __builtin_bit_cast(uint16_t, h);
}
__device__ __forceinline__ float bf2f(uint16_t h) {
    uint32_t u = ((uint32_t)h) << 16;
    return __builtin_bit_cast(float, u);
}
__device__ __forceinline__ bf16x8 pack8(f32x4 a, f32x4 b) {
    union { bf16x8 v; uint16_t s[8]; } o;
    o.s[0] = f2bf(a[0]); o.s[1] = f2bf(a[1]); o.s[2] = f2bf(a[2]); o.s[3] = f2bf(a[3]);
    o.s[4] = f2bf(b[0]); o.s[5] = f2bf(b[1]); o.s[6] = f2bf(b[2]); o.s[7] = f2bf(b[3]);
    return o.v;
}

// ---------------------------------------------------------------------------
// K1: qkv = x @ qkv_w^T + qkv_b   (M=4096, N=2304, K=768), fp32 in, bf16 out
// grid (32, 18), block 256
// ---------------------------------------------------------------------------
__global__ __launch_bounds__(256) void k_qkv(
    const float* __restrict__ x, const float* __restrict__ w,
    const float* __restrict__ bias, uint16_t* __restrict__ qb,
    uint16_t* __restrict__ kb, uint16_t* __restrict__ vtb)
{
    __shared__ uint16_t As[128][40];
    __shared__ uint16_t Bs[128][40];
    const int t = threadIdx.x;
    const int lane = t & 63;
    const int wv = t >> 6, wr = wv >> 1, wc = wv & 1;
    const int row0 = blockIdx.x * 128, col0 = blockIdx.y * 128;
    const int sr = t >> 1, sc = (t & 1) << 4;
    const float* xa = x + (size_t)(row0 + sr) * 768 + sc;
    const float* wa = w + (size_t)(col0 + sr) * 768 + sc;

    f32x4 ra[4], rb[4];
#pragma unroll
    for (int i = 0; i < 4; ++i) { ra[i] = *(const f32x4*)(xa + i * 4); rb[i] = *(const f32x4*)(wa + i * 4); }

    f32x4 acc[4][4];
    const f32x4 z = {0.f, 0.f, 0.f, 0.f};
#pragma unroll
    for (int i = 0; i < 4; ++i)
#pragma unroll
        for (int j = 0; j < 4; ++j) acc[i][j] = z;

    const int fr = lane & 15, fo = (lane >> 4) << 3;

    for (int kt = 0; kt < 24; ++kt) {
        __syncthreads();
        *(bf16x8*)&As[sr][sc]     = pack8(ra[0], ra[1]);
        *(bf16x8*)&As[sr][sc + 8] = pack8(ra[2], ra[3]);
        *(bf16x8*)&Bs[sr][sc]     = pack8(rb[0], rb[1]);
        *(bf16x8*)&Bs[sr][sc + 8] = pack8(rb[2], rb[3]);
        __syncthreads();
        if (kt < 23) {
            xa += 32; wa += 32;
#pragma unroll
            for (int i = 0; i < 4; ++i) { ra[i] = *(const f32x4*)(xa + i * 4); rb[i] = *(const f32x4*)(wa + i * 4); }
        }
        bf16x8 af[4], bfv[4];
#pragma unroll
        for (int mi = 0; mi < 4; ++mi) af[mi]  = *(const bf16x8*)&As[wr * 64 + mi * 16 + fr][fo];
#pragma unroll
        for (int ni = 0; ni < 4; ++ni) bfv[ni] = *(const bf16x8*)&Bs[wc * 64 + ni * 16 + fr][fo];
#pragma unroll
        for (int mi = 0; mi < 4; ++mi)
#pragma unroll
            for (int ni = 0; ni < 4; ++ni)
                acc[mi][ni] = __builtin_amdgcn_mfma_f32_16x16x32_bf16(af[mi], bfv[ni], acc[mi][ni], 0, 0, 0);
    }

    const int rgr = (lane >> 4) << 2;
#pragma unroll
    for (int ni = 0; ni < 4; ++ni) {
        const int Jc = col0 + wc * 64 + ni * 16 + fr;
        const float bv = bias[Jc];
        const int which = Jc / 768;
        const int rem = Jc - which * 768;
        const int h = rem >> 6, d = rem & 63;
#pragma unroll
        for (int mi = 0; mi < 4; ++mi) {
#pragma unroll
            for (int i = 0; i < 4; ++i) {
                const int R = row0 + wr * 64 + mi * 16 + rgr + i;
                const int b = R >> 10, n = R & 1023;
                const uint16_t hv = f2bf(acc[mi][ni][i] + bv);
                if (which == 0)      qb [((size_t)(b * 12 + h) * 1024 + n) * 64 + d] = hv;
                else if (which == 1) kb [((size_t)(b * 12 + h) * 1024 + n) * 64 + d] = hv;
                else                 vtb[((size_t)(b * 12 + h) * 64 + d) * 1024 + n] = hv;
            }
        }
    }
}

// ---------------------------------------------------------------------------
// K2: S[bh, n, m] = sum_d q[bh,n,d] * k[bh,m,d]   (raw scores, bf16 out)
// grid (8, 8, 48), block 256
// ---------------------------------------------------------------------------
__global__ __launch_bounds__(256) void k_qk(
    const uint16_t* __restrict__ q, const uint16_t* __restrict__ k,
    uint16_t* __restrict__ S)
{
    const int t = threadIdx.x, lane = t & 63;
    const int wv = t >> 6, wr = wv >> 1, wc = wv & 1;
    const int bh = blockIdx.z;
    q += (size_t)bh << 16;
    k += (size_t)bh << 16;
    S += (size_t)bh << 20;
    const int R0 = blockIdx.x * 128 + wr * 64;
    const int C0 = blockIdx.y * 128 + wc * 64;
    const int fr = lane & 15, fo = (lane >> 4) << 3;

    bf16x8 af[4][2], bfv[4][2];
#pragma unroll
    for (int mi = 0; mi < 4; ++mi)
#pragma unroll
        for (int ks = 0; ks < 2; ++ks)
            af[mi][ks] = *(const bf16x8*)(q + (R0 + mi * 16 + fr) * 64 + ks * 32 + fo);
#pragma unroll
    for (int ni = 0; ni < 4; ++ni)
#pragma unroll
        for (int ks = 0; ks < 2; ++ks)
            bfv[ni][ks] = *(const bf16x8*)(k + (C0 + ni * 16 + fr) * 64 + ks * 32 + fo);

    f32x4 acc[4][4];
    const f32x4 z = {0.f, 0.f, 0.f, 0.f};
#pragma unroll
    for (int i = 0; i < 4; ++i)
#pragma unroll
        for (int j = 0; j < 4; ++j) acc[i][j] = z;
#pragma unroll
    for (int mi = 0; mi < 4; ++mi)
#pragma unroll
        for (int ni = 0; ni < 4; ++ni) {
            acc[mi][ni] = __builtin_amdgcn_mfma_f32_16x16x32_bf16(af[mi][0], bfv[ni][0], acc[mi][ni], 0, 0, 0);
            acc[mi][ni] = __builtin_amdgcn_mfma_f32_16x16x32_bf16(af[mi][1], bfv[ni][1], acc[mi][ni], 0, 0, 0);
        }

    const int rgr = (lane >> 4) << 2;
#pragma unroll
    for (int mi = 0; mi < 4; ++mi)
#pragma unroll
        for (int ni = 0; ni < 4; ++ni)
#pragma unroll
            for (int i = 0; i < 4; ++i) {
                const int R = R0 + mi * 16 + rgr + i;
                const int C = C0 + ni * 16 + fr;
                S[(size_t)R * 1024 + C] = f2bf(acc[mi][ni][i]);
            }
}

// ---------------------------------------------------------------------------
// K3: per (b,n) row: softmax per head, uncertainty = sigmoid(du_w @ qk + du_b),
//     attn = softmax + unc * r (bf16 in-place over S). am/un fp32 (nontemporal).
// grid 4096, block 256 (each thread owns m = {4t..4t+3} for all 12 heads)
// ---------------------------------------------------------------------------
__global__ __launch_bounds__(256) void k_soft(
    uint16_t* __restrict__ S, const float* __restrict__ r,
    const float* __restrict__ du_w, const float* __restrict__ du_b,
    float* __restrict__ am, float* __restrict__ un)
{
    const int bn = blockIdx.x;
    const int b = bn >> 10, n = bn & 1023;
    const int t = threadIdx.x;
    const int lane = t & 63, wv = t >> 6;

    __shared__ float red[4][12];
    __shared__ float bmax[12];
    __shared__ float binv[12];

    const size_t pbase = ((size_t)(b * 12) * 1024 + n) * 1024;  // + (h<<20) + m
    const int m0 = t * 4;

    float s[12][4];
#pragma unroll
    for (int h = 0; h < 12; ++h) {
        const uint2 u = *(const uint2*)(S + pbase + ((size_t)h << 20) + m0);
        s[h][0] = bf2f((uint16_t)(u.x & 0xFFFFu));
        s[h][1] = bf2f((uint16_t)(u.x >> 16));
        s[h][2] = bf2f((uint16_t)(u.y & 0xFFFFu));
        s[h][3] = bf2f((uint16_t)(u.y >> 16));
    }

    // block max per head
    float lm[12];
#pragma unroll
    for (int h = 0; h < 12; ++h)
        lm[h] = fmaxf(fmaxf(s[h][0], s[h][1]), fmaxf(s[h][2], s[h][3]));
#pragma unroll
    for (int off = 32; off >= 1; off >>= 1)
#pragma unroll
        for (int h = 0; h < 12; ++h) lm[h] = fmaxf(lm[h], __shfl_xor(lm[h], off));
    if (lane == 0)
#pragma unroll
        for (int h = 0; h < 12; ++h) red[wv][h] = lm[h];
    __syncthreads();
    if (t < 12)
        bmax[t] = fmaxf(fmaxf(red[0][t], red[1][t]), fmaxf(red[2][t], red[3][t]));
    __syncthreads();

    // block sum of exp per head (exp recomputed later; don't keep p[] live)
    const float CE = 0.125f * 1.44269504088896f;   // scale * log2(e)
    float ls[12];
#pragma unroll
    for (int h = 0; h < 12; ++h) {
        const float mx = bmax[h];
        ls[h] = exp2f((s[h][0] - mx) * CE) + exp2f((s[h][1] - mx) * CE)
              + exp2f((s[h][2] - mx) * CE) + exp2f((s[h][3] - mx) * CE);
    }
#pragma unroll
    for (int off = 32; off >= 1; off >>= 1)
#pragma unroll
        for (int h = 0; h < 12; ++h) ls[h] += __shfl_xor(ls[h], off);
    if (lane == 0)
#pragma unroll
        for (int h = 0; h < 12; ++h) red[wv][h] = ls[h];
    __syncthreads();
    if (t < 12)
        binv[t] = 1.f / (red[0][t] + red[1][t] + red[2][t] + red[3][t]);
    __syncthreads();

    const float L2E = 1.44269504088896f;
#pragma unroll
    for (int o = 0; o < 12; ++o) {
        float a[4];
        const float bo = du_b[o];                 // uniform -> scalar load
        a[0] = bo; a[1] = bo; a[2] = bo; a[3] = bo;
#pragma unroll
        for (int h = 0; h < 12; ++h) {
            const float wv_ = du_w[o * 12 + h];   // uniform -> scalar load
            a[0] += wv_ * s[h][0];
            a[1] += wv_ * s[h][1];
            a[2] += wv_ * s[h][2];
            a[3] += wv_ * s[h][3];
        }
        const float mx = bmax[o], inv = binv[o];
        const size_t idx = pbase + ((size_t)o << 20) + m0;
        const f32x4 rv = __builtin_nontemporal_load((const f32x4*)(r + idx));
        f32x4 pm, uo;
        uint16_t at[4];
#pragma unroll
        for (int j = 0; j < 4; ++j) {
            const float u = 1.f / (1.f + exp2f(-a[j] * L2E));
            const float p = exp2f((s[o][j] - mx) * CE) * inv;
            pm[j] = p; uo[j] = u;
            at[j] = f2bf(p + u * rv[j]);
        }
        __builtin_nontemporal_store(pm, (f32x4*)(am + idx));
        __builtin_nontemporal_store(uo, (f32x4*)(un + idx));
        uint2 pk;
        pk.x = (uint32_t)at[0] | ((uint32_t)at[1] << 16);
        pk.y = (uint32_t)at[2] | ((uint32_t)at[3] << 16);
        *(uint2*)(S + idx) = pk;
    }
}

// ---------------------------------------------------------------------------
// K4: out_h[b,n,h*64+d] = sum_m attn[bh,n,m] * vT[bh,d,m]  (bf16 out)
// grid (16, 48), block 256 (4 waves x 16 rows)
// ---------------------------------------------------------------------------
__global__ __launch_bounds__(256) void k_pv(
    const uint16_t* __restrict__ attn, const uint16_t* __restrict__ vt,
    uint16_t* __restrict__ oh)
{
    const int t = threadIdx.x, lane = t & 63, wv = t >> 6;
    const int bh = blockIdx.y, b = bh / 12, h = bh - b * 12;
    attn += (size_t)bh << 20;
    vt   += (size_t)bh << 16;
    const int R0 = blockIdx.x * 64 + wv * 16;
    const int fr = lane & 15, fo = (lane >> 4) << 3;

    f32x4 acc[4];
    const f32x4 z = {0.f, 0.f, 0.f, 0.f};
#pragma unroll
    for (int j = 0; j < 4; ++j) acc[j] = z;

#pragma unroll 2
    for (int kk = 0; kk < 32; ++kk) {
        const int k0 = kk * 32;
        const bf16x8 af = *(const bf16x8*)(attn + (size_t)(R0 + fr) * 1024 + k0 + fo);
        bf16x8 bfv[4];
#pragma unroll
        for (int ni = 0; ni < 4; ++ni)
            bfv[ni] = *(const bf16x8*)(vt + (size_t)(ni * 16 + fr) * 1024 + k0 + fo);
#pragma unroll
        for (int ni = 0; ni < 4; ++ni)
            acc[ni] = __builtin_amdgcn_mfma_f32_16x16x32_bf16(af, bfv[ni], acc[ni], 0, 0, 0);
    }

    const int rgr = (lane >> 4) << 2;
#pragma unroll
    for (int ni = 0; ni < 4; ++ni)
#pragma unroll
        for (int i = 0; i < 4; ++i) {
            const int R = R0 + rgr + i;
            const int d = ni * 16 + fr;
            oh[((size_t)b * 1024 + R) * 768 + h * 64 + d] = f2bf(acc[ni][i]);
        }
}

// ---------------------------------------------------------------------------
// K5: out = out_h @ proj_w^T + proj_b   (M=4096, N=768, K=768), fp32 out
// grid (32, 12), block 256
// ---------------------------------------------------------------------------
__global__ __launch_bounds__(256) void k_proj(
    const uint16_t* __restrict__ a, const float* __restrict__ w,
    const float* __restrict__ bias, float* __restrict__ out)
{
    const int t = threadIdx.x, lane = t & 63;
    const int wv = t >> 6, wr = wv >> 1, wc = wv & 1;
    const int R0 = blockIdx.x * 128 + wr * 64;
    const int J0 = blockIdx.y * 64 + wc * 32;
    const int fr = lane & 15, fo = (lane >> 4) << 3;

    f32x4 acc[4][2];
    const f32x4 z = {0.f, 0.f, 0.f, 0.f};
#pragma unroll
    for (int i = 0; i < 4; ++i) { acc[i][0] = z; acc[i][1] = z; }

    for (int kk = 0; kk < 24; ++kk) {
        const int k0 = kk * 32;
        bf16x8 af[4], bfv[2];
#pragma unroll
        for (int mi = 0; mi < 4; ++mi)
            af[mi] = *(const bf16x8*)(a + (size_t)(R0 + mi * 16 + fr) * 768 + k0 + fo);
#pragma unroll
        for (int ni = 0; ni < 2; ++ni) {
            const float* wp = w + (size_t)(J0 + ni * 16 + fr) * 768 + k0 + fo;
            bfv[ni] = pack8(*(const f32x4*)wp, *(const f32x4*)(wp + 4));
        }
#pragma unroll
        for (int mi = 0; mi < 4; ++mi)
#pragma unroll
            for (int ni = 0; ni < 2; ++ni)
                acc[mi][ni] = __builtin_amdgcn_mfma_f32_16x16x32_bf16(af[mi], bfv[ni], acc[mi][ni], 0, 0, 0);
    }

    const int rgr = (lane >> 4) << 2;
#pragma unroll
    for (int ni = 0; ni < 2; ++ni) {
        const int Jc = J0 + ni * 16 + fr;
        const float bv = bias[Jc];
#pragma unroll
        for (int mi = 0; mi < 4; ++mi)
#pragma unroll
            for (int i = 0; i < 4; ++i) {
                const int R = R0 + mi * 16 + rgr + i;
                out[(size_t)R * 768 + Jc] = acc[mi][ni][i] + bv;
            }
    }
}

// ---------------------------------------------------------------------------
extern "C" void kernel_launch(void* const* d_in, const int* in_sizes, int n_in,
                              void* d_out, int out_size, void* d_ws, size_t ws_size,
                              hipStream_t stream)
{
    const float* x      = (const float*)d_in[0];
    const float* r      = (const float*)d_in[1];
    const float* qkv_w  = (const float*)d_in[2];
    const float* qkv_b  = (const float*)d_in[3];
    const float* proj_w = (const float*)d_in[4];
    const float* proj_b = (const float*)d_in[5];
    const float* du_w   = (const float*)d_in[6];
    const float* du_b   = (const float*)d_in[7];

    float* out       = (float*)d_out;                    // [4,1024,768]
    float* attn_mean = out + 3145728;                    // [4,12,1024,1024]
    float* unc       = attn_mean + 50331648;             // [4,12,1024,1024]

    uint16_t* ws  = (uint16_t*)d_ws;
    uint16_t* qb  = ws;                 // q[b,h,n,d]
    uint16_t* kb  = qb + 3145728;       // k[b,h,n,d]
    uint16_t* vtb = kb + 3145728;       // vT[b,h,d,n]
    uint16_t* S   = vtb + 3145728;      // qk scores -> attn (in place)
    uint16_t* oh  = S + 50331648;       // out_h[b,n,h*64+d]

    k_qkv <<<dim3(32, 18), 256, 0, stream>>>(x, qkv_w, qkv_b, qb, kb, vtb);
    k_qk  <<<dim3(8, 8, 48), 256, 0, stream>>>(qb, kb, S);
    k_soft<<<dim3(4096), 256, 0, stream>>>(S, r, du_w, du_b, attn_mean, unc);
    k_pv  <<<dim3(16, 48), 256, 0, stream>>>(S, vtb, oh);
    k_proj<<<dim3(32, 12), 256, 0, stream>>>(oh, proj_w, proj_b, out);
}